// Round 7
// baseline (232.625 us; speedup 1.0000x reference)
//
#include <hip/hip_runtime.h>
#include <math.h>

#define T_STEPS 16
#define NTOK 2048
#define WAVES_PER_BLOCK 8
#define BLOCK (WAVES_PER_BLOCK * 64)

typedef _Float16 h2 __attribute__((ext_vector_type(2)));
#define BC(T, x) __builtin_bit_cast(T, x)

// Packed-f16 approx distance for one 64-token block.
// Codebook in LDS as uint4 {x01, y01, x23, y23} (packed f16 pairs, 16 B/token).
// Quake-style packed rsqrt hack: y = 0x59ba - (q>>1) per half (mask keeps halves
// independent; no borrow since (q>>1)&0x7fff <= 0x3dff < 0x59ba).
#define DT16(k, dst) { \
    const uint4 v = ldsH[((k) << 6) | lane]; \
    const h2 dx01 = BC(h2, v.x) + ux01, dy01 = BC(h2, v.y) + uy01; \
    const h2 dx23 = BC(h2, v.z) + ux23, dy23 = BC(h2, v.w) + uy23; \
    const h2 q01 = dx01 * dx01 + dy01 * dy01; \
    const h2 q23 = dx23 * dx23 + dy23 * dy23; \
    const unsigned y01 = 0x59ba59bau - ((BC(unsigned, q01) >> 1) & 0x7fff7fffu); \
    const unsigned y23 = 0x59ba59bau - ((BC(unsigned, q23) >> 1) & 0x7fff7fffu); \
    const h2 s = q01 * BC(h2, y01) + q23 * BC(h2, y23); \
    dst = s.x + s.y; \
    dmh = dst < dmh ? dst : dmh; }

// pass 1 pair: blocks 2j, 2j+1 -> one packed u32; sched_barrier every 2nd pair
// (4 ds_reads in flight: hides LDS latency without the R4 hoist-everything spill)
#define PASS1(j, pk) { \
    _Float16 dA_, dB_; \
    DT16(2*(j),   dA_) \
    DT16(2*(j)+1, dB_) \
    h2 p_; p_.x = dA_; p_.y = dB_; \
    pk = BC(unsigned, p_); \
    if ((j) & 1) __builtin_amdgcn_sched_barrier(0); }

// exact f32 eval of one block, codebook read from global (L2-hot, 64 KB)
#define EXACT(k) { \
    const int n = ((k) << 6) | lane; \
    const float4 A  = gsrc[2 * n]; \
    const float4 Bv = gsrc[2 * n + 1]; \
    float dx, dy; \
    dx = A.x  + u0x; dy = A.y  + u0y; const float q0 = fmaf(dy, dy, dx * dx); \
    dx = A.z  + u1x; dy = A.w  + u1y; const float q1 = fmaf(dy, dy, dx * dx); \
    dx = Bv.x + u2x; dy = Bv.y + u2y; const float q2 = fmaf(dy, dy, dx * dx); \
    dx = Bv.z + u3x; dy = Bv.w + u3y; const float q3 = fmaf(dy, dy, dx * dx); \
    const float d = (__builtin_amdgcn_sqrtf(q0) + __builtin_amdgcn_sqrtf(q1)) + \
                    (__builtin_amdgcn_sqrtf(q2) + __builtin_amdgcn_sqrtf(q3)); \
    const bool upd = (d < bestd) || (d == bestd && n < bestn); \
    bestd = upd ? d : bestd; \
    bestn = upd ? n : bestn; }

#define PASS2(j, pk) { \
    const h2 h_ = BC(h2, pk); \
    if (__any((float)h_.x <= thr)) EXACT(2*(j)) \
    if (__any((float)h_.y <= thr)) EXACT(2*(j)+1) }

#define FOR_P(M) \
    M(0,pk00)  M(1,pk01)  M(2,pk02)  M(3,pk03)  M(4,pk04)  M(5,pk05)  M(6,pk06)  M(7,pk07) \
    M(8,pk08)  M(9,pk09)  M(10,pk10) M(11,pk11) M(12,pk12) M(13,pk13) M(14,pk14) M(15,pk15)

#define DECL_P(j, pk) unsigned pk;

__global__ __launch_bounds__(BLOCK)
void tokenizer_kernel(const float* __restrict__ data,
                      const float* __restrict__ tok,
                      float* __restrict__ out,
                      int B) {
    __shared__ uint4 ldsH[NTOK];   // f16 codebook: {x01, y01, x23, y23} per token

    const float4* gsrc = (const float4*)tok;
    for (int n = threadIdx.x; n < NTOK; n += BLOCK) {
        const float4 a = gsrc[2 * n];       // (x0,y0,x1,y1)
        const float4 c = gsrc[2 * n + 1];   // (x2,y2,x3,y3)
        h2 x01; x01.x = (_Float16)a.x; x01.y = (_Float16)a.z;
        h2 y01; y01.x = (_Float16)a.y; y01.y = (_Float16)a.w;
        h2 x23; x23.x = (_Float16)c.x; x23.y = (_Float16)c.z;
        h2 y23; y23.x = (_Float16)c.y; y23.y = (_Float16)c.w;
        uint4 o; o.x = BC(unsigned, x01); o.y = BC(unsigned, y01);
                 o.z = BC(unsigned, x23); o.w = BC(unsigned, y23);
        ldsH[n] = o;
    }
    __syncthreads();

    const int wave = threadIdx.x >> 6;
    const int lane = threadIdx.x & 63;
    const int b = blockIdx.x * WAVES_PER_BLOCK + wave;
    if (b >= B) return;

    const float* db = data + (size_t)b * (T_STEPS * 3);
    float* outIdx  = out;
    float* outPos  = out + (size_t)B * T_STEPS;
    float* outHead = out + (size_t)B * T_STEPS * 3;

    float cpx = 0.f, cpy = 0.f;    // carry: prev_pos
    float rc = 1.f, rs = 0.f;      // carry: cos/sin(prev_head)

    for (int t = 0; t < T_STEPS; ++t) {
        const float px = db[t * 3 + 0];
        const float py = db[t * 3 + 1];
        const float hh = db[t * 3 + 2];

        // gt contour corners (lf, rf, rb, lb)
        float sh, ch;
        sincosf(hh, &sh, &ch);
        const float hc = 0.5f * ch, hs = 0.5f * sh;
        const float lc = 4.8f * hc, ls = 4.8f * hs;
        const float wc = 2.0f * hc, ws = 2.0f * hs;

        // e_j = cp - g_j ; u_j = R^T e_j  =>  dist_j = || f_j + u_j ||
        const float e0x = cpx - (px + lc - ws), e0y = cpy - (py + ls + wc);
        const float e1x = cpx - (px + lc + ws), e1y = cpy - (py + ls - wc);
        const float e2x = cpx - (px - lc + ws), e2y = cpy - (py - ls - wc);
        const float e3x = cpx - (px - lc - ws), e3y = cpy - (py - ls + wc);
        const float u0x = rc * e0x + rs * e0y, u0y = rc * e0y - rs * e0x;
        const float u1x = rc * e1x + rs * e1y, u1y = rc * e1y - rs * e1x;
        const float u2x = rc * e2x + rs * e2y, u2y = rc * e2y - rs * e2x;
        const float u3x = rc * e3x + rs * e3y, u3y = rc * e3y - rs * e3x;

        // packed-f16 u vectors for pass 1
        h2 ux01; ux01.x = (_Float16)u0x; ux01.y = (_Float16)u1x;
        h2 uy01; uy01.x = (_Float16)u0y; uy01.y = (_Float16)u1y;
        h2 ux23; ux23.x = (_Float16)u2x; ux23.y = (_Float16)u3x;
        h2 uy23; uy23.x = (_Float16)u2y; uy23.y = (_Float16)u3y;

        // ---- pass 1: packed-f16 approx d~ for all 2048 tokens
        FOR_P(DECL_P)
        _Float16 dmh = (_Float16)65504.f;
        FOR_P(PASS1)

        // wave-wide min of approx distance (f32 shuffles)
        float dmin = (float)dmh;
        #pragma unroll
        for (int off = 32; off > 0; off >>= 1)
            dmin = fminf(dmin, __shfl_xor(dmin, off, 64));
        // 1.25 covers eps <= 11.1%; budget: hack ~4% + f16 rounding/cancel ~2-3%
        const float thr = dmin * 1.25f;

        // ---- pass 2: exact f32 v_sqrt eval only for firing blocks
        float bestd = 3.4e38f;
        int   bestn = 0;
        FOR_P(PASS2)

        // wave argmin reduction, lowest-index tie-break (matches jnp.argmin)
        #pragma unroll
        for (int off = 32; off > 0; off >>= 1) {
            const float od = __shfl_xor(bestd, off, 64);
            const int   on = __shfl_xor(bestn, off, 64);
            if (od < bestd || (od == bestd && on < bestn)) { bestd = od; bestn = on; }
        }

        // selected contour in global frame (exact f32 codebook, uniform L2 read;
        // same arithmetic as the R1-passing version)
        const float4 A  = gsrc[2 * bestn];
        const float4 Bv = gsrc[2 * bestn + 1];
        const float c0x = A.x  * rc - A.y  * rs + cpx, c0y = A.x  * rs + A.y  * rc + cpy;
        const float c1x = A.z  * rc - A.w  * rs + cpx, c1y = A.z  * rs + A.w  * rc + cpy;
        const float c2x = Bv.x * rc - Bv.y * rs + cpx, c2y = Bv.x * rs + Bv.y * rc + cpy;
        const float c3x = Bv.z * rc - Bv.w * rs + cpx, c3y = Bv.z * rs + Bv.w * rc + cpy;

        const float npx = 0.25f * (((c0x + c1x) + c2x) + c3x);
        const float npy = 0.25f * (((c0y + c1y) + c2y) + c3y);
        const float dxx = c0x - c3x, dyy = c0y - c3y;
        const float nh  = atan2f(dyy, dxx);

        if (lane == 0) {
            const int ot = b * T_STEPS + t;
            outIdx[ot]         = (float)bestn;
            outPos[2 * ot]     = npx;
            outPos[2 * ot + 1] = npy;
            outHead[ot]        = nh;
        }

        // carry: rotation directly from the contour edge (= cos/sin(atan2))
        cpx = npx; cpy = npy;
        const float len = __builtin_amdgcn_sqrtf(fmaf(dyy, dyy, dxx * dxx));
        rc = dxx / len;
        rs = dyy / len;
    }
}

extern "C" void kernel_launch(void* const* d_in, const int* in_sizes, int n_in,
                              void* d_out, int out_size, void* d_ws, size_t ws_size,
                              hipStream_t stream) {
    const float* data = (const float*)d_in[0];
    const float* tok  = (const float*)d_in[1];
    float* out = (float*)d_out;

    const int B = in_sizes[0] / (T_STEPS * 3);   // 4096
    const int grid = (B + WAVES_PER_BLOCK - 1) / WAVES_PER_BLOCK;

    tokenizer_kernel<<<grid, BLOCK, 0, stream>>>(data, tok, out, B);
}